// Round 1
// baseline (240.594 us; speedup 1.0000x reference)
//
#include <hip/hip_runtime.h>
#include <cstdint>
#include <cstddef>

#define NSPIN 2
#define NPART 16
#define DDIM  512
#define NION  8

// LDS float offsets
#define WT_OFF    0                       // 2*16*516 = 16512
#define XS_OFF    16512                   // 2*8192  = 16384 (double buffer)
#define RS_OFF    (XS_OFF + 16384)        // 384
#define PART_OFF  (RS_OFF + 384)          // 2048
#define LINP_OFF  (PART_OFF + 2048)       // 256  [16][16]
#define LINJ_OFF  (LINP_OFF + 256)        // 320  [16][20]
#define ENV_OFF   (LINJ_OFF + 320)        // 320  [16][20]
#define DETS_OFF  (ENV_OFF + 320)         // 16
#define LDS_FLOATS (DETS_OFF + 16)
#define LDS_BYTES  (LDS_FLOATS * 4)       // 144960 B

__device__ __forceinline__ void fma4(float& acc, const float4& x, const float4& w) {
    acc = fmaf(x.x, w.x, acc);
    acc = fmaf(x.y, w.y, acc);
    acc = fmaf(x.z, w.z, acc);
    acc = fmaf(x.w, w.w, acc);
}

__global__ void __launch_bounds__(256)
ppdet_kernel(const float* __restrict__ EQ, const float* __restrict__ RE,
             const float* __restrict__ WL, const float* __restrict__ BL,
             const float* __restrict__ AE, const float* __restrict__ WI,
             float* __restrict__ OUT)
{
    extern __shared__ float ls[];
    const int t  = threadIdx.x;
    const int s  = blockIdx.x >> 9;           // spin 0/1
    const int b0 = (blockIdx.x & 511) * 4;    // 4 b's per block

    // ---- stage W (transposed, pad 516) into LDS: WT[h][k][f] ----
    {
        const float* Wg = WL + s * (2 * DDIM * NPART);   // (1024,16)
        #pragma unroll
        for (int it = 0; it < 16; ++it) {
            int idx = it * 256 + t;          // f4 index 0..4095
            int f   = idx >> 2;              // 0..1023
            int kq  = (idx & 3) << 2;        // 0,4,8,12
            const float4 v = *(const float4*)&Wg[f * 16 + kq];
            float* dst = &ls[WT_OFF + (f >> 9) * 8256 + (f & 511)];
            dst[(kq + 0) * 516] = v.x;
            dst[(kq + 1) * 516] = v.y;
            dst[(kq + 2) * 516] = v.z;
            dst[(kq + 3) * 516] = v.w;
        }
    }

    const int ke = t >> 4;     // env col k / det matrix p
    const int jr = t & 15;     // env row j / det row / reducer k

    // ---- hoist A_env, w_ion, b_lin into registers ----
    float Ar[3][3][NION];
    float wir[NION];
    {
        const float* Ag = AE + s * (3 * 3 * NION * NPART);
        #pragma unroll
        for (int pp = 0; pp < 3; ++pp)
            #pragma unroll
            for (int q = 0; q < 3; ++q)
                #pragma unroll
                for (int i = 0; i < NION; ++i)
                    Ar[pp][q][i] = Ag[((pp * 3 + q) * NION + i) * NPART + ke];
        #pragma unroll
        for (int i = 0; i < NION; ++i)
            wir[i] = WI[s * (NION * NPART) + i * NPART + ke];
    }
    const float blv = BL[s * NPART + jr];

    // GEMM role
    const int kk = t & 15;
    const int rq = (t >> 4) & 3;
    const int fh = t >> 6;

    float4 xpre[8];
    float4 rpre;

    auto issue_x = [&](int b) {
        const float4* src = (const float4*)(EQ + (size_t)(b * 32 + s * 16) * DDIM);
        #pragma unroll
        for (int i2 = 0; i2 < 8; ++i2) xpre[i2] = src[i2 * 256 + t];
    };
    auto issue_r = [&](int b) {
        if (t < 96) rpre = ((const float4*)(RE + (size_t)(b * 32 + s * 16) * 24))[t];
    };
    issue_x(b0); issue_r(b0);

    for (int ib = 0; ib < 4; ++ib) {
        const int b   = b0 + ib;
        const int buf = ib & 1;
        float* xb = &ls[XS_OFF + buf * 8192];

        // write-late staging (XOR-swizzled rows: f4 ^ (r&7))
        #pragma unroll
        for (int i2 = 0; i2 < 8; ++i2) {
            int f4lin = i2 * 256 + t;
            int r = f4lin >> 7, f4l = f4lin & 127;
            *(float4*)&xb[r * DDIM + ((f4l ^ (r & 7)) << 2)] = xpre[i2];
        }
        if (t < 96) ((float4*)&ls[RS_OFF])[t] = rpre;
        __syncthreads();                                   // C
        if (ib < 3) { issue_x(b + 1); issue_r(b + 1); }    // overlap with compute

        // ---- GEMM: lin_p (W1), lin_j (W2); 4 rows/thread, f-quarter per wave ----
        float accp[4] = {0.f, 0.f, 0.f, 0.f};
        float accj[4] = {0.f, 0.f, 0.f, 0.f};
        {
            const float* w1  = &ls[WT_OFF + kk * 516 + fh * 128];
            const float* w2  = w1 + 8256;
            const float* xr0 = &xb[(rq     ) * DDIM];
            const float* xr1 = &xb[(rq +  4) * DDIM];
            const float* xr2 = &xb[(rq +  8) * DDIM];
            const float* xr3 = &xb[(rq + 12) * DDIM];
            #pragma unroll 4
            for (int i2 = 0; i2 < 32; ++i2) {
                const int f4g = fh * 32 + i2;
                const int o0 = (f4g ^ rq) << 2;
                const int o1 = (f4g ^ (rq + 4)) << 2;
                const float4 w1v = *(const float4*)&w1[i2 * 4];
                const float4 w2v = *(const float4*)&w2[i2 * 4];
                const float4 x0 = *(const float4*)&xr0[o0];
                const float4 x1 = *(const float4*)&xr1[o1];
                const float4 x2 = *(const float4*)&xr2[o0];
                const float4 x3 = *(const float4*)&xr3[o1];
                fma4(accp[0], x0, w1v); fma4(accj[0], x0, w2v);
                fma4(accp[1], x1, w1v); fma4(accj[1], x1, w2v);
                fma4(accp[2], x2, w1v); fma4(accj[2], x2, w2v);
                fma4(accp[3], x3, w1v); fma4(accj[3], x3, w2v);
            }
        }
        #pragma unroll
        for (int e = 0; e < 4; ++e) {
            ls[PART_OFF + e * 256 + t]       = accp[e];
            ls[PART_OFF + (4 + e) * 256 + t] = accj[e];
        }
        __syncthreads();                                   // A

        // reduce 4-way f-split (wave 0 only) and publish lin_p / lin_j(+b)
        if (t < 64) {
            #pragma unroll
            for (int e = 0; e < 8; ++e) {
                float v = ls[PART_OFF + e * 256 + t]
                        + ls[PART_OFF + e * 256 + t + 64]
                        + ls[PART_OFF + e * 256 + t + 128]
                        + ls[PART_OFF + e * 256 + t + 192];
                int m = e & 3;
                int r = ((t >> 4) & 3) + 4 * m;
                if (e < 4) ls[LINP_OFF + r * 16 + (t & 15)] = v;
                else       ls[LINJ_OFF + r * 20 + (t & 15)] = v + blv;
            }
        }
        // env[j][k] (all threads; A/w_ion in regs, r from LDS)
        {
            float ev = 0.f;
            const float* rsl = &ls[RS_OFF + jr * 24];
            #pragma unroll
            for (int i = 0; i < NION; ++i) {
                float r0 = rsl[i * 3 + 0], r1 = rsl[i * 3 + 1], r2 = rsl[i * 3 + 2];
                float ss = 0.f;
                #pragma unroll
                for (int q = 0; q < 3; ++q) {
                    float a = fmaf(r0, Ar[0][q][i], fmaf(r1, Ar[1][q][i], r2 * Ar[2][q][i]));
                    ss = fmaf(a, a, ss);
                }
                ev = fmaf(wir[i], __expf(-__builtin_amdgcn_sqrtf(ss)), ev);
            }
            ls[ENV_OFF + jr * 20 + ke] = ev;
        }
        __syncthreads();                                   // B

        // ---- build M_p column... rows: thread (p=ke, row jr) holds row jr of M_p ----
        float Mr[16];
        {
            const float4* lp4 = (const float4*)&ls[LINP_OFF + ke * 16];
            const float4* lj4 = (const float4*)&ls[LINJ_OFF + jr * 20];
            const float4* ev4 = (const float4*)&ls[ENV_OFF + jr * 20];
            #pragma unroll
            for (int cq = 0; cq < 4; ++cq) {
                float4 a = lp4[cq], bb = lj4[cq], e = ev4[cq];
                Mr[cq * 4 + 0] = (a.x + bb.x) * e.x;
                Mr[cq * 4 + 1] = (a.y + bb.y) * e.y;
                Mr[cq * 4 + 2] = (a.z + bb.z) * e.z;
                Mr[cq * 4 + 3] = (a.w + bb.w) * e.w;
            }
        }
        // ---- det via partially-pivoted GE, 16 lanes = 16 rows, no physical swap ----
        float detv = 1.f;
        unsigned sel = 0u;
        int inv = 0;
        bool mysel = false;
        const int lanebase = t & 48;
        #pragma unroll
        for (int c = 0; c < 16; ++c) {
            float key = mysel ? -3.4e38f : fabsf(Mr[c]);
            int idx = jr;
            #pragma unroll
            for (int mm = 8; mm >= 1; mm >>= 1) {
                float ok = __shfl_xor(key, mm, 64);
                int  oi  = __shfl_xor(idx, mm, 64);
                bool gt = (ok > key) || (ok == key && oi < idx);
                key = gt ? ok : key;
                idx = gt ? oi : idx;
            }
            const int src = lanebase | idx;
            const float pv  = __shfl(Mr[c], src, 64);
            const float rpv = __builtin_amdgcn_rcpf(pv);
            float f = (mysel || (jr == idx)) ? 0.f : Mr[c] * rpv;
            inv += __popc(sel >> (idx + 1));
            sel |= (1u << idx);
            mysel = mysel || (jr == idx);
            detv *= pv;
            #pragma unroll
            for (int k2 = c + 1; k2 < 16; ++k2) {
                float Pk = __shfl(Mr[k2], src, 64);
                Mr[k2] = fmaf(-f, Pk, Mr[k2]);
            }
        }
        if (inv & 1) detv = -detv;
        if (jr == 0) ls[DETS_OFF + ke] = detv;
        __syncthreads();                                   // D

        // ---- epilogue: out = x * det, fully coalesced float4 stores ----
        {
            float* outp = OUT + (size_t)(b * 32 + s * 16) * DDIM;
            #pragma unroll
            for (int i2 = 0; i2 < 8; ++i2) {
                int f4lin = i2 * 256 + t;
                int r = f4lin >> 7, f4l = f4lin & 127;
                float4 xv = *(const float4*)&xb[r * DDIM + ((f4l ^ (r & 7)) << 2)];
                float dt = ls[DETS_OFF + r];
                float4 o = make_float4(xv.x * dt, xv.y * dt, xv.z * dt, xv.w * dt);
                ((float4*)outp)[f4lin] = o;
            }
        }
    }
}

extern "C" void kernel_launch(void* const* d_in, const int* in_sizes, int n_in,
                              void* d_out, int out_size, void* d_ws, size_t ws_size,
                              hipStream_t stream) {
    const float* EQ = (const float*)d_in[0];
    const float* RE = (const float*)d_in[1];
    const float* WL = (const float*)d_in[2];
    const float* BL = (const float*)d_in[3];
    const float* AE = (const float*)d_in[4];
    const float* WI = (const float*)d_in[5];
    float* OUT = (float*)d_out;
    (void)in_sizes; (void)n_in; (void)out_size; (void)d_ws; (void)ws_size;

    hipFuncSetAttribute((const void*)ppdet_kernel,
                        hipFuncAttributeMaxDynamicSharedMemorySize, LDS_BYTES);
    ppdet_kernel<<<dim3(1024), dim3(256), LDS_BYTES, stream>>>(EQ, RE, WL, BL, AE, WI, OUT);
}

// Round 2
// 173.847 us; speedup vs baseline: 1.3839x; 1.3839x over previous
//
#include <hip/hip_runtime.h>
#include <cstdint>
#include <cstddef>

#define NSPIN 2
#define NPART 16
#define DDIM  512
#define NION  8

// LDS float offsets (total 20240 floats = 80960 B -> 2 blocks/CU)
#define WT_OFF    0                        // 2*16*516 = 16512
#define RS_OFF    16512                    // 2*384 = 768 (double buffer)
#define PART_OFF  (RS_OFF + 768)           // 2048
#define LINP_OFF  (PART_OFF + 2048)        // 256  [16][16]
#define LINJ_OFF  (LINP_OFF + 256)         // 320  [16][20]
#define ENV_OFF   (LINJ_OFF + 320)         // 320  [16][20]
#define DETS_OFF  (ENV_OFF + 320)          // 16
#define LDS_FLOATS (DETS_OFF + 16)
#define LDS_BYTES  (LDS_FLOATS * 4)        // 80960 B

__device__ __forceinline__ void fma4(float& acc, const float4& x, const float4& w) {
    acc = fmaf(x.x, w.x, acc);
    acc = fmaf(x.y, w.y, acc);
    acc = fmaf(x.z, w.z, acc);
    acc = fmaf(x.w, w.w, acc);
}

__global__ void __launch_bounds__(256)
ppdet_kernel(const float* __restrict__ EQ, const float* __restrict__ RE,
             const float* __restrict__ WL, const float* __restrict__ BL,
             const float* __restrict__ AE, const float* __restrict__ WI,
             float* __restrict__ OUT)
{
    extern __shared__ float ls[];
    const int t  = threadIdx.x;
    const int s  = blockIdx.x >> 9;           // spin 0/1
    const int b0 = (blockIdx.x & 511) * 4;    // 4 b's per block

    // ---- stage W (transposed, pad 516) into LDS: WT[h][k][f] ----
    {
        const float* Wg = WL + s * (2 * DDIM * NPART);   // (1024,16)
        #pragma unroll
        for (int it = 0; it < 16; ++it) {
            int idx = it * 256 + t;          // f4 index 0..4095
            int f   = idx >> 2;              // 0..1023
            int kq  = (idx & 3) << 2;        // 0,4,8,12
            const float4 v = *(const float4*)&Wg[f * 16 + kq];
            float* dst = &ls[WT_OFF + (f >> 9) * 8256 + (f & 511)];
            dst[(kq + 0) * 516] = v.x;
            dst[(kq + 1) * 516] = v.y;
            dst[(kq + 2) * 516] = v.z;
            dst[(kq + 3) * 516] = v.w;
        }
    }
    // r_ei for first iteration into RS buffer 0
    if (t < 96) {
        float4 r0 = ((const float4*)(RE + (size_t)(b0 * 32 + s * 16) * 24))[t];
        ((float4*)&ls[RS_OFF])[t] = r0;
    }

    const int ke = t >> 4;     // env col k / det matrix p
    const int jr = t & 15;     // env row j / det row

    // ---- hoist A_env, w_ion, b_lin into registers ----
    float Ar[3][3][NION];
    float wir[NION];
    {
        const float* Ag = AE + s * (3 * 3 * NION * NPART);
        #pragma unroll
        for (int pp = 0; pp < 3; ++pp)
            #pragma unroll
            for (int q = 0; q < 3; ++q)
                #pragma unroll
                for (int i = 0; i < NION; ++i)
                    Ar[pp][q][i] = Ag[((pp * 3 + q) * NION + i) * NPART + ke];
        #pragma unroll
        for (int i = 0; i < NION; ++i)
            wir[i] = WI[s * (NION * NPART) + i * NPART + ke];
    }
    const float blv = BL[s * NPART + jr];

    // GEMM role: wave fh handles f-quarter, lanes = kk(16) x rq(4)
    const int kk = t & 15;
    const int rq = (t >> 4) & 3;
    const int fh = t >> 6;

    __syncthreads();   // W + RS0 staged

    for (int ib = 0; ib < 4; ++ib) {
        const int b = b0 + ib;
        const float* xg = EQ + (size_t)(b * 32 + s * 16) * DDIM;

        // r_ei prefetch for next iteration (written to RS[buf^1] later)
        float4 rpre;
        if (ib < 3 && t < 96)
            rpre = ((const float4*)(RE + (size_t)((b + 1) * 32 + s * 16) * 24))[t];

        // ---- GEMM: x direct from global (16 kk-lanes broadcast), W from LDS ----
        float accp[4] = {0.f, 0.f, 0.f, 0.f};
        float accj[4] = {0.f, 0.f, 0.f, 0.f};
        {
            const float*  w1 = &ls[WT_OFF + kk * 516 + fh * 128];
            const float*  w2 = w1 + 8256;
            const float4* g0 = (const float4*)(xg + (rq     ) * DDIM + fh * 128);
            const float4* g1 = (const float4*)(xg + (rq +  4) * DDIM + fh * 128);
            const float4* g2 = (const float4*)(xg + (rq +  8) * DDIM + fh * 128);
            const float4* g3 = (const float4*)(xg + (rq + 12) * DDIM + fh * 128);
            #pragma unroll 4
            for (int i2 = 0; i2 < 32; ++i2) {
                const float4 w1v = *(const float4*)&w1[i2 * 4];
                const float4 w2v = *(const float4*)&w2[i2 * 4];
                const float4 x0 = g0[i2];
                const float4 x1 = g1[i2];
                const float4 x2 = g2[i2];
                const float4 x3 = g3[i2];
                fma4(accp[0], x0, w1v); fma4(accj[0], x0, w2v);
                fma4(accp[1], x1, w1v); fma4(accj[1], x1, w2v);
                fma4(accp[2], x2, w1v); fma4(accj[2], x2, w2v);
                fma4(accp[3], x3, w1v); fma4(accj[3], x3, w2v);
            }
        }

        // coalesced x prefetch for the epilogue (latency hidden under reduce/env/det)
        float4 xpre[8];
        {
            const float4* src = (const float4*)xg;
            #pragma unroll
            for (int i2 = 0; i2 < 8; ++i2) xpre[i2] = src[i2 * 256 + t];
        }

        #pragma unroll
        for (int e = 0; e < 4; ++e) {
            ls[PART_OFF + e * 256 + t]       = accp[e];
            ls[PART_OFF + (4 + e) * 256 + t] = accj[e];
        }
        __syncthreads();                                   // A

        // reduce 4-way f-split (wave 0 only) and publish lin_p / lin_j(+b)
        if (t < 64) {
            #pragma unroll
            for (int e = 0; e < 8; ++e) {
                float v = ls[PART_OFF + e * 256 + t]
                        + ls[PART_OFF + e * 256 + t + 64]
                        + ls[PART_OFF + e * 256 + t + 128]
                        + ls[PART_OFF + e * 256 + t + 192];
                int m = e & 3;
                int r = ((t >> 4) & 3) + 4 * m;
                if (e < 4) ls[LINP_OFF + r * 16 + (t & 15)] = v;
                else       ls[LINJ_OFF + r * 20 + (t & 15)] = v + blv;
            }
        }
        // env[j][k] (all threads; A/w_ion in regs, r from LDS double buffer)
        {
            float ev = 0.f;
            const float* rsl = &ls[RS_OFF + (ib & 1) * 384 + jr * 24];
            #pragma unroll
            for (int i = 0; i < NION; ++i) {
                float r0 = rsl[i * 3 + 0], r1 = rsl[i * 3 + 1], r2 = rsl[i * 3 + 2];
                float ss = 0.f;
                #pragma unroll
                for (int q = 0; q < 3; ++q) {
                    float a = fmaf(r0, Ar[0][q][i], fmaf(r1, Ar[1][q][i], r2 * Ar[2][q][i]));
                    ss = fmaf(a, a, ss);
                }
                ev = fmaf(wir[i], __expf(-__builtin_amdgcn_sqrtf(ss)), ev);
            }
            ls[ENV_OFF + jr * 20 + ke] = ev;
        }
        // write next iteration's r_ei into the other RS buffer
        if (ib < 3 && t < 96)
            ((float4*)&ls[RS_OFF + ((ib + 1) & 1) * 384])[t] = rpre;
        __syncthreads();                                   // B

        // ---- build M rows: thread (p=ke, row jr) holds row jr of M_p ----
        float Mr[16];
        {
            const float4* lp4 = (const float4*)&ls[LINP_OFF + ke * 16];
            const float4* lj4 = (const float4*)&ls[LINJ_OFF + jr * 20];
            const float4* ev4 = (const float4*)&ls[ENV_OFF + jr * 20];
            #pragma unroll
            for (int cq = 0; cq < 4; ++cq) {
                float4 a = lp4[cq], bb = lj4[cq], e = ev4[cq];
                Mr[cq * 4 + 0] = (a.x + bb.x) * e.x;
                Mr[cq * 4 + 1] = (a.y + bb.y) * e.y;
                Mr[cq * 4 + 2] = (a.z + bb.z) * e.z;
                Mr[cq * 4 + 3] = (a.w + bb.w) * e.w;
            }
        }
        // ---- det via partially-pivoted GE, 16 lanes = 16 rows, no physical swap ----
        float detv = 1.f;
        unsigned sel = 0u;
        int inv = 0;
        bool mysel = false;
        const int lanebase = t & 48;
        #pragma unroll
        for (int c = 0; c < 16; ++c) {
            float key = mysel ? -3.4e38f : fabsf(Mr[c]);
            int idx = jr;
            #pragma unroll
            for (int mm = 8; mm >= 1; mm >>= 1) {
                float ok = __shfl_xor(key, mm, 64);
                int  oi  = __shfl_xor(idx, mm, 64);
                bool gt = (ok > key) || (ok == key && oi < idx);
                key = gt ? ok : key;
                idx = gt ? oi : idx;
            }
            const int src = lanebase | idx;
            const float pv  = __shfl(Mr[c], src, 64);
            const float rpv = __builtin_amdgcn_rcpf(pv);
            float f = (mysel || (jr == idx)) ? 0.f : Mr[c] * rpv;
            inv += __popc(sel >> (idx + 1));
            sel |= (1u << idx);
            mysel = mysel || (jr == idx);
            detv *= pv;
            #pragma unroll
            for (int k2 = c + 1; k2 < 16; ++k2) {
                float Pk = __shfl(Mr[k2], src, 64);
                Mr[k2] = fmaf(-f, Pk, Mr[k2]);
            }
        }
        if (inv & 1) detv = -detv;
        if (jr == 0) ls[DETS_OFF + ke] = detv;
        __syncthreads();                                   // D

        // ---- epilogue: out = xpre * det, fully coalesced float4 stores ----
        {
            float* outp = OUT + (size_t)(b * 32 + s * 16) * DDIM;
            #pragma unroll
            for (int i2 = 0; i2 < 8; ++i2) {
                int f4lin = i2 * 256 + t;
                int r = f4lin >> 7;
                float dt = ls[DETS_OFF + r];
                float4 xv = xpre[i2];
                ((float4*)outp)[f4lin] = make_float4(xv.x * dt, xv.y * dt, xv.z * dt, xv.w * dt);
            }
        }
    }
}

extern "C" void kernel_launch(void* const* d_in, const int* in_sizes, int n_in,
                              void* d_out, int out_size, void* d_ws, size_t ws_size,
                              hipStream_t stream) {
    const float* EQ = (const float*)d_in[0];
    const float* RE = (const float*)d_in[1];
    const float* WL = (const float*)d_in[2];
    const float* BL = (const float*)d_in[3];
    const float* AE = (const float*)d_in[4];
    const float* WI = (const float*)d_in[5];
    float* OUT = (float*)d_out;
    (void)in_sizes; (void)n_in; (void)out_size; (void)d_ws; (void)ws_size;

    hipFuncSetAttribute((const void*)ppdet_kernel,
                        hipFuncAttributeMaxDynamicSharedMemorySize, LDS_BYTES);
    ppdet_kernel<<<dim3(1024), dim3(256), LDS_BYTES, stream>>>(EQ, RE, WL, BL, AE, WI, OUT);
}

// Round 3
// 87.602 us; speedup vs baseline: 2.7464x; 1.9845x over previous
//
#include <hip/hip_runtime.h>
#include <cstdint>
#include <cstddef>

#define NSPIN 2
#define NPART 16
#define DDIM  512
#define NION  8

// LDS float offsets
#define WB_FLOATS 8192                    // bf16 W fragments: 2 halves *16 ksteps *64 lanes *8 bf16 = 32768 B
#define RS_OFF    8192                    // 4 b * 16 rows * 24 floats = 1536
#define LINP_OFF  (RS_OFF + 1536)         // 4*16*16 = 1024
#define LINJ_OFF  (LINP_OFF + 1024)       // 4*16*20 = 1280
#define ENV_OFF   (LINJ_OFF + 1280)       // 4*16*20 = 1280
#define DETS_OFF  (ENV_OFF + 1280)        // 64
#define LDS_FLOATS (DETS_OFF + 64)
#define LDS_BYTES  (LDS_FLOATS * 4)       // 53504 B -> 3 blocks/CU

typedef short bf16x8 __attribute__((ext_vector_type(8)));
typedef float f32x4  __attribute__((ext_vector_type(4)));

__device__ __forceinline__ short bfc(float x) {  // f32 -> bf16 (RNE)
    unsigned u = __float_as_uint(x);
    u += 0x7FFFu + ((u >> 16) & 1u);
    return (short)(u >> 16);
}

// DPP helpers: 16-lane-row rotate + op (VALU pipe, no LDS)
#define DPPMAXU(k, ctrl) { unsigned o_ = (unsigned)__builtin_amdgcn_update_dpp(0, (int)(k), (ctrl), 0xF, 0xF, true); (k) = (k) > o_ ? (k) : o_; }
#define DPPADDF(v, ctrl) { float o_ = __int_as_float(__builtin_amdgcn_update_dpp(0, __float_as_int(v), (ctrl), 0xF, 0xF, true)); (v) += o_; }

__global__ void __launch_bounds__(256, 3)
ppdet_kernel(const float* __restrict__ EQ, const float* __restrict__ RE,
             const float* __restrict__ WL, const float* __restrict__ BL,
             const float* __restrict__ AE, const float* __restrict__ WI,
             float* __restrict__ OUT)
{
    extern __shared__ float ls[];
    const int t  = threadIdx.x;
    const int s  = blockIdx.x >> 9;           // spin
    const int b0 = (blockIdx.x & 511) * 4;    // 4 b's per block

    const int l  = t & 63;                    // lane in wave
    const int w  = t >> 6;                    // wave id (0..3)
    const int c  = l & 15;                    // MFMA row/col lane index
    const int h4 = l >> 4;                    // MFMA k-group
    const int jr = t & 15;                    // row index (env/det)
    const int ke = t >> 4;                    // k-column slot (env) / matrix p (det)

    // ---- stage W as bf16 MFMA B-fragments: slot = (half*16+ks)*64+lane ----
    {
        const float* Wg = WL + (size_t)s * (2 * DDIM * NPART);
        ushort* wb = (ushort*)ls;
        #pragma unroll
        for (int it = 0; it < 8; ++it) {
            int slot = it * 256 + t;              // 0..2047
            int half = slot >> 10;
            int ks   = (slot >> 6) & 15;
            int lane = slot & 63;
            int cc2  = lane & 15, hh = lane >> 4;
            const float* src = Wg + ((size_t)(half * 512 + ks * 32 + hh * 8)) * NPART + cc2;
            ushort u[8];
            #pragma unroll
            for (int e = 0; e < 8; ++e) u[e] = (ushort)bfc(src[e * NPART]);
            uint4 pk;
            pk.x = (unsigned)u[0] | ((unsigned)u[1] << 16);
            pk.y = (unsigned)u[2] | ((unsigned)u[3] << 16);
            pk.z = (unsigned)u[4] | ((unsigned)u[5] << 16);
            pk.w = (unsigned)u[6] | ((unsigned)u[7] << 16);
            *(uint4*)&wb[slot * 8] = pk;
        }
    }
    // ---- stage r_ei for all 4 b's ----
    #pragma unroll
    for (int it = 0; it < 2; ++it) {
        int idx = it * 256 + t;
        if (idx < 384) {
            int bi = idx / 96, rem = idx % 96;
            ((float4*)(ls + RS_OFF))[idx] =
                ((const float4*)RE)[((size_t)(b0 + bi) * 32 + s * 16) * 6 + rem];
        }
    }
    __syncthreads();   // barrier 1: W + RS staged

    // ---- GEMM via MFMA: wave w handles b = b0+w ----
    {
        const float* xg = EQ + ((size_t)(b0 + w) * 32 + s * 16 + c) * DDIM + h4 * 8;
        const ushort* wb = (const ushort*)ls;
        f32x4 accp = {0.f, 0.f, 0.f, 0.f}, accj = {0.f, 0.f, 0.f, 0.f};
        #pragma unroll
        for (int ks = 0; ks < 16; ++ks) {
            float4 a0 = *(const float4*)(xg + ks * 32);
            float4 a1 = *(const float4*)(xg + ks * 32 + 4);
            bf16x8 af;
            af[0] = bfc(a0.x); af[1] = bfc(a0.y); af[2] = bfc(a0.z); af[3] = bfc(a0.w);
            af[4] = bfc(a1.x); af[5] = bfc(a1.y); af[6] = bfc(a1.z); af[7] = bfc(a1.w);
            bf16x8 bf1 = *(const bf16x8*)(wb + (size_t)(ks * 64 + l) * 8);
            bf16x8 bf2 = *(const bf16x8*)(wb + (size_t)((16 + ks) * 64 + l) * 8);
            accp = __builtin_amdgcn_mfma_f32_16x16x32_bf16(af, bf1, accp, 0, 0, 0);
            accj = __builtin_amdgcn_mfma_f32_16x16x32_bf16(af, bf2, accj, 0, 0, 0);
        }
        const float blv = BL[s * NPART + c];
        #pragma unroll
        for (int q = 0; q < 4; ++q) {     // C: row = h4*4+q, col = c
            ls[LINP_OFF + (w * 16 + h4 * 4 + q) * 16 + c] = accp[q];
            ls[LINJ_OFF + (w * 16 + h4 * 4 + q) * 20 + c] = accj[q] + blv;
        }
    }

    // ---- env: Gram trick, G = A·A^T per (ion, ke) ----
    {
        float G0[8], G1[8], G2[8], G3[8], G4[8], G5[8], wir[8];
        const float* Ag = AE + (size_t)s * (9 * NION * NPART);
        #pragma unroll
        for (int i = 0; i < 8; ++i) {
            float a00 = Ag[((0 * 3 + 0) * NION + i) * NPART + ke];
            float a01 = Ag[((0 * 3 + 1) * NION + i) * NPART + ke];
            float a02 = Ag[((0 * 3 + 2) * NION + i) * NPART + ke];
            float a10 = Ag[((1 * 3 + 0) * NION + i) * NPART + ke];
            float a11 = Ag[((1 * 3 + 1) * NION + i) * NPART + ke];
            float a12 = Ag[((1 * 3 + 2) * NION + i) * NPART + ke];
            float a20 = Ag[((2 * 3 + 0) * NION + i) * NPART + ke];
            float a21 = Ag[((2 * 3 + 1) * NION + i) * NPART + ke];
            float a22 = Ag[((2 * 3 + 2) * NION + i) * NPART + ke];
            G0[i] = a00 * a00 + a01 * a01 + a02 * a02;
            G1[i] = a10 * a10 + a11 * a11 + a12 * a12;
            G2[i] = a20 * a20 + a21 * a21 + a22 * a22;
            G3[i] = a00 * a10 + a01 * a11 + a02 * a12;
            G4[i] = a00 * a20 + a01 * a21 + a02 * a22;
            G5[i] = a10 * a20 + a11 * a21 + a12 * a22;
            wir[i] = WI[(size_t)s * (NION * NPART) + i * NPART + ke];
        }
        #pragma unroll
        for (int ib = 0; ib < 4; ++ib) {
            const float* rs = ls + RS_OFF + (ib * 16 + jr) * 24;
            float ev = 0.f;
            #pragma unroll
            for (int i = 0; i < 8; ++i) {
                float r0 = rs[i * 3], r1 = rs[i * 3 + 1], r2 = rs[i * 3 + 2];
                float ss = r0 * r0 * G0[i];
                ss = fmaf(r1 * r1, G1[i], ss);
                ss = fmaf(r2 * r2, G2[i], ss);
                float tcr = r0 * r1 * G3[i];
                tcr = fmaf(r0 * r2, G4[i], tcr);
                tcr = fmaf(r1 * r2, G5[i], tcr);
                ss = fmaf(2.f, tcr, ss);
                ss = fmaxf(ss, 0.f);
                ev = fmaf(wir[i], __expf(-__builtin_amdgcn_sqrtf(ss)), ev);
            }
            ls[ENV_OFF + (ib * 16 + jr) * 20 + ke] = ev;
        }
    }
    __syncthreads();   // barrier 2: LIN + ENV ready

    // ---- det: 4 passes; matrix (b=ib, p=ke); 16-lane groups; DS-free GE ----
    for (int ib = 0; ib < 4; ++ib) {
        float Mr[16];
        const float* lp = ls + LINP_OFF + (ib * 16 + ke) * 16;
        const float* lj = ls + LINJ_OFF + (ib * 16 + jr) * 20;
        const float* ev = ls + ENV_OFF  + (ib * 16 + jr) * 20;
        #pragma unroll
        for (int cq = 0; cq < 4; ++cq) {
            float4 a = *(const float4*)(lp + cq * 4);
            float4 bb = *(const float4*)(lj + cq * 4);
            float4 e = *(const float4*)(ev + cq * 4);
            Mr[cq * 4 + 0] = (a.x + bb.x) * e.x;
            Mr[cq * 4 + 1] = (a.y + bb.y) * e.y;
            Mr[cq * 4 + 2] = (a.z + bb.z) * e.z;
            Mr[cq * 4 + 3] = (a.w + bb.w) * e.w;
        }
        float detv = 1.f;
        unsigned sel = 0u;
        int inv = 0;
        bool msel = false;
        #pragma unroll
        for (int cc = 0; cc < 16; ++cc) {
            // packed argmax over rows (DPP, VALU-only)
            unsigned key = msel ? 0u
                : ((__float_as_uint(fabsf(Mr[cc])) & 0xFFFFFFF0u) | (unsigned)jr);
            DPPMAXU(key, 0x121); DPPMAXU(key, 0x122); DPPMAXU(key, 0x124); DPPMAXU(key, 0x128);
            const int idx = (int)(key & 15u);
            const bool ispiv = (jr == idx);
            // pivot-row broadcast via select + ror-add (exactly one nonzero)
            float Pr[16];
            #pragma unroll
            for (int k2 = cc; k2 < 16; ++k2) {
                float tt = ispiv ? Mr[k2] : 0.f;
                DPPADDF(tt, 0x121); DPPADDF(tt, 0x122); DPPADDF(tt, 0x124); DPPADDF(tt, 0x128);
                Pr[k2] = tt;
            }
            const float pv = Pr[cc];
            const float f = (msel || ispiv || pv == 0.f) ? 0.f
                          : Mr[cc] * __builtin_amdgcn_rcpf(pv);
            inv += __popc(sel >> (idx + 1));
            sel |= (1u << idx);
            msel = msel || ispiv;
            detv *= pv;
            #pragma unroll
            for (int k2 = cc + 1; k2 < 16; ++k2)
                Mr[k2] = fmaf(-f, Pr[k2], Mr[k2]);
        }
        if (inv & 1) detv = -detv;
        if (jr == 0) ls[DETS_OFF + ib * 16 + ke] = detv;
    }
    __syncthreads();   // barrier 3: DETS ready

    // ---- epilogue: out = x * det, coalesced float4 ----
    #pragma unroll
    for (int ib = 0; ib < 4; ++ib) {
        const size_t base = ((size_t)(b0 + ib) * 32 + s * 16) * DDIM;
        #pragma unroll
        for (int i2 = 0; i2 < 8; ++i2) {
            int f4i = i2 * 256 + t;
            float dt = ls[DETS_OFF + ib * 16 + (f4i >> 7)];
            float4 xv = ((const float4*)(EQ + base))[f4i];
            float4 o = make_float4(xv.x * dt, xv.y * dt, xv.z * dt, xv.w * dt);
            ((float4*)(OUT + base))[f4i] = o;
        }
    }
}

extern "C" void kernel_launch(void* const* d_in, const int* in_sizes, int n_in,
                              void* d_out, int out_size, void* d_ws, size_t ws_size,
                              hipStream_t stream) {
    const float* EQ = (const float*)d_in[0];
    const float* RE = (const float*)d_in[1];
    const float* WL = (const float*)d_in[2];
    const float* BL = (const float*)d_in[3];
    const float* AE = (const float*)d_in[4];
    const float* WI = (const float*)d_in[5];
    float* OUT = (float*)d_out;
    (void)in_sizes; (void)n_in; (void)out_size; (void)d_ws; (void)ws_size;

    hipFuncSetAttribute((const void*)ppdet_kernel,
                        hipFuncAttributeMaxDynamicSharedMemorySize, LDS_BYTES);
    ppdet_kernel<<<dim3(1024), dim3(256), LDS_BYTES, stream>>>(EQ, RE, WL, BL, AE, WI, OUT);
}